// Round 1
// 5214.215 us; speedup vs baseline: 1.3472x; 1.3472x over previous
//
#include <hip/hip_runtime.h>
#include <cstdint>
#include <cstddef>

// ---------------------------------------------------------------------------
// 2-layer LSTM, T=512, B=64, IN=H=1024. Persistent kernel, 256 blocks x 512
// threads, layers pipelined at lag 1.
// R5 changes (theory: step time is fan-out READ volume, not flag latency —
// R4's sync-only changes gave ~0; 96 MB/step of L2/L3 reads at ~50-60 B/cyc/CU
// is ~3 us/block serialized with the sync chain):
//  - Layer0 repartitioned Bs=32/R=64 (16 units x 32 batches per block): x and
//    h1 read volume per block halves (384 -> 192 KB/step). Same VGPR budget
//    (64 rows x 256-K slice per wave = 128 VGPRs of weights).
//  - Layer0 x-part (x@Wih) computed BEFORE the flag gate each step (depends
//    only on the input tensor) — 128 KB read + 256 MFMAs overlap straggler
//    wait. Only h-waves poll (64 bg-peer flags, own flag excluded).
//  - Layer1 recurrence reads f16 h2 ring (4 slabs) instead of fp32 out
//    (256 -> 128 KB/step). Ring reuses addresses -> agent-scope atomic loads
//    (per-XCD L2 would serve 4-step-stale lines). out is now a pure output
//    (plain stores, not on the visibility chain).
//  - h1 history in [bg][jb][bm][8] layout: producer writes stay one
//    contiguous 1KB region per block; consumer 16-B lane reads are
//    16-lane-contiguous 256-B runs.
// Per-step fan-out traffic 96 -> 57 MB; L0 gated read only 64 KB.
// ---------------------------------------------------------------------------

typedef _Float16 f16;
typedef _Float16 f16x8 __attribute__((ext_vector_type(8)));
typedef _Float16 f16x4 __attribute__((ext_vector_type(4)));
typedef float    f32x4 __attribute__((ext_vector_type(4)));
typedef unsigned long long u64;

#define T_STEPS 512
#define BH      65536                 /* 64 batch x 1024 hidden */
#define NBLK    256

// workspace layout (bytes)
static const size_t OFF_FLAG = 0;            // 256 x 4 B flags
static const size_t OFF_H2   = 0x1000;       // h2 ring: 4 slabs * BH * 2B = 512 KB
static const size_t OFF_H1   = 0x90000;      // h1 history: 513 slabs * BH * 2B = 64.1 MB
// h1 slab layout: slab*65536 + bg*32768 + jb*256 + bm*8 + e   (f16)
//   bg = batch>>5, bm = batch&31, jb = unit>>3, e = unit&7
// h2 slab layout: slab*65536 + jb*512 + b*8 + e                (f16)

// ---------------------------------------------------------------------------
__global__ void prep_kernel(f16* __restrict__ h1, unsigned* __restrict__ flags)
{
    const int NONES = BH / 4;                 // slab 0 = ones (h init)
    const int NZ    = NBLK / 4;
    int tid    = blockIdx.x * blockDim.x + threadIdx.x;
    int stride = gridDim.x * blockDim.x;
    f16x4 one = { (f16)1.f, (f16)1.f, (f16)1.f, (f16)1.f };
    uint4 z = { 0u, 0u, 0u, 0u };
    for (int i = tid; i < NONES + NZ; i += stride) {
        if (i < NONES) ((f16x4*)h1)[i] = one;
        else           ((uint4*)flags)[i - NONES] = z;
    }
}

__device__ __forceinline__ float sigm(float x) { return 1.f/(1.f + __expf(-x)); }
__device__ __forceinline__ float tanh_f(float x) {
    float e = __expf(-2.f*fabsf(x));
    float r = (1.f - e)/(1.f + e);
    return x >= 0.f ? r : -r;
}
__device__ __forceinline__ f16x8 cvt8(float4 a, float4 b) {
    f16x8 r;
    r[0]=(f16)a.x; r[1]=(f16)a.y; r[2]=(f16)a.z; r[3]=(f16)a.w;
    r[4]=(f16)b.x; r[5]=(f16)b.y; r[6]=(f16)b.z; r[7]=(f16)b.w;
    return r;
}

// L2-bypass (device-scope) poll loads.
__device__ __forceinline__ unsigned poll1(const unsigned* p) {
    unsigned r;
    asm volatile("global_load_dword %0, %1, off sc1\n\ts_waitcnt vmcnt(0)"
                 : "=v"(r) : "v"(p) : "memory");
    return r;
}
__device__ __forceinline__ uint2 poll2(const unsigned* p) {
    uint2 r;
    asm volatile("global_load_dwordx2 %0, %1, off sc1\n\ts_waitcnt vmcnt(0)"
                 : "=v"(r) : "v"(p) : "memory");
    return r;
}
// L2-bypass (device-scope) flag publish.
__device__ __forceinline__ void flag_store(unsigned* p, unsigned v) {
    asm volatile("global_store_dword %0, %1, off sc1" :: "v"(p), "v"(v) : "memory");
}
// Coherent 16-B load as 2x agent-scope u64 (h2 ring slabs reuse addresses,
// so the consumer's per-XCD L2 may hold stale lines; agent loads bypass it).
__device__ __forceinline__ f16x8 ald16(const f16* p) {
    union { u64 q[2]; f16x8 v; } u;
    u.q[0] = __hip_atomic_load((const u64*)p,       __ATOMIC_RELAXED, __HIP_MEMORY_SCOPE_AGENT);
    u.q[1] = __hip_atomic_load((const u64*)(p + 4), __ATOMIC_RELAXED, __HIP_MEMORY_SCOPE_AGENT);
    return u.v;
}

// ---------------------------------------------------------------------------
// Partition:
//  Layer 0 (bid 0..127): bg = bid>>6 (batch group of 32), jg = bid&63
//    (16 hidden units j0=jg*16). 8 waves = 8 K-slices of 256 over K=2048
//    ([x | h1]); waves 0-3 = x slices (ungated), waves 4-7 = h1 slices (gated
//    on the 64 bg-peer flags). 4 n-tiles per wave = gates i,f,g,o of 16 units.
//  Layer 1 (bid 128..255): jg1 = bid&127 (8 units j0=jg1*8), Bs=64, verbatim
//    R3/R4 structure: kq = wave>>1 (K-quarter of 2048), mh = wave&1.
//    kq 0-1: h1 input (gated on all 128 L0 flags); kq 2-3: h2 f16 ring
//    (gated on all 128 L1 flags; ones at s==1).
// Step s: L0 computes h1 token s -> slab s+1; L1 computes out token s-1
//    (reads h1 slab s + h2 ring slab (s-1)&3), writes out + h2 slab s&3.
// ---------------------------------------------------------------------------
__global__ __launch_bounds__(512, 2)
void lstm_kernel(const float* __restrict__ x,
                 const float* __restrict__ wih0, const float* __restrict__ whh0,
                 const float* __restrict__ b0,
                 const float* __restrict__ wih1, const float* __restrict__ whh1,
                 const float* __restrict__ b1,
                 f16* __restrict__ h1, f16* __restrict__ h2,
                 float* __restrict__ out, unsigned* __restrict__ flags)
{
    __shared__ float lds_part[16384];
    __shared__ float lds_out[2048];

    const int tid   = threadIdx.x;
    const int bid   = blockIdx.x;
    const int layer = bid >> 7;
    const int wave  = tid >> 6, lane = tid & 63;
    const int l15   = lane & 15, l4 = lane >> 4;

    f16x8 Bf[32];
    f32x4 acc[8];
    const f32x4 zz = { 0.f, 0.f, 0.f, 0.f };

    if (layer == 0) {
        // =================== LAYER 0 ===================
        const int bg = bid >> 6, jg = bid & 63, j0 = jg << 4;
        const int kq = wave;                    // 0..3: x-slice, 4..7: h-slice

        // weight preload: 4 n-tiles (gates) x 8 kc, K-slice (kq&3)*256
        {
            const float* wsrc = (kq < 4) ? wih0 : whh0;
            const int kp = (kq & 3) * 256;
#pragma unroll
            for (int nt = 0; nt < 4; nt++) {
                const float* rp = wsrc + (size_t)(nt*1024 + j0 + l15)*1024 + kp + l4*8;
#pragma unroll
                for (int kc = 0; kc < 8; kc++) {
                    float4 a = *(const float4*)(rp + kc*32);
                    float4 b = *(const float4*)(rp + kc*32 + 4);
                    Bf[nt*8 + kc] = cvt8(a, b);
                }
            }
#pragma unroll
            for (int i = 0; i < 32; i++) asm volatile("" : "+v"(Bf[i]));
        }

        // elementwise cell ownership: store offset == tid (contiguous region)
        const int u  = ((tid >> 8) << 3) | (tid & 7);   // unit 0..15
        const int bm = (tid >> 3) & 31;                 // batch-in-group 0..31
        const float bi  = b0[j0+u],      bff = b0[1024+j0+u];
        const float bgg = b0[2048+j0+u], boo = b0[3072+j0+u];
        float c = 0.f;
        const int m_ = bm >> 4, r_ = bm & 15;
        const int lanei = ((r_ >> 2) << 4) | u, rr = r_ & 3;

        for (int s = 0; s <= T_STEPS; s++) {
            const bool act = (s < T_STEPS);
            if (act) {
#pragma unroll
                for (int i = 0; i < 8; i++) acc[i] = zz;
                if (kq < 4) {
                    // ---- x-part: ungated, overlaps peers' straggle ----
                    const float* a0 = x + (size_t)s*BH + (size_t)(bg*32 + l15)*1024 + kq*256 + l4*8;
                    const float* a1 = a0 + 16*1024;
#pragma unroll
                    for (int kc = 0; kc < 8; kc++) {
                        f16x8 A0 = cvt8(*(const float4*)(a0 + kc*32), *(const float4*)(a0 + kc*32 + 4));
                        f16x8 A1 = cvt8(*(const float4*)(a1 + kc*32), *(const float4*)(a1 + kc*32 + 4));
#pragma unroll
                        for (int nt = 0; nt < 4; nt++) {
                            acc[nt]   = __builtin_amdgcn_mfma_f32_16x16x32_f16(A0, Bf[nt*8+kc], acc[nt],   0,0,0);
                            acc[4+nt] = __builtin_amdgcn_mfma_f32_16x16x32_f16(A1, Bf[nt*8+kc], acc[4+nt], 0,0,0);
                        }
                    }
                } else {
                    // ---- h-part: gate on bg-peer flags >= s (skip own) ----
                    if (s > 0) {
                        const unsigned* p = flags + bg*64 + lane;
                        const bool skip = (lane == jg);
                        for (;;) {
                            unsigned v = poll1(p);
                            if (__all(skip || (v >= (unsigned)s))) break;
                            __builtin_amdgcn_s_sleep(2);
                        }
                    }
                    const f16* a0 = h1 + (size_t)s*BH + bg*32768 + ((kq-4)*32 + l4)*256 + l15*8;
                    const f16* a1 = a0 + 128;
#pragma unroll
                    for (int kc = 0; kc < 8; kc++) {
                        f16x8 A0 = *(const f16x8*)(a0 + kc*1024);
                        f16x8 A1 = *(const f16x8*)(a1 + kc*1024);
#pragma unroll
                        for (int nt = 0; nt < 4; nt++) {
                            acc[nt]   = __builtin_amdgcn_mfma_f32_16x16x32_f16(A0, Bf[nt*8+kc], acc[nt],   0,0,0);
                            acc[4+nt] = __builtin_amdgcn_mfma_f32_16x16x32_f16(A1, Bf[nt*8+kc], acc[4+nt], 0,0,0);
                        }
                    }
                }
                // partials -> LDS, region = wave, slot = m*4+nt
                const int pb = wave*2048 + lane*4;
#pragma unroll
                for (int i = 0; i < 8; i++)
                    *(f32x4*)&lds_part[pb + i*256] = acc[i];
            }
            __syncthreads();
            if (act) {
                f32x4 sum = *(const f32x4*)&lds_part[tid*4];
#pragma unroll
                for (int q = 1; q < 8; q++)
                    sum += *(const f32x4*)&lds_part[q*2048 + tid*4];
                *(f32x4*)&lds_out[tid*4] = sum;
            }
            __syncthreads();
            if (act) {
                float gi = lds_out[(m_*4+0)*256 + lanei*4 + rr] + bi;
                float gf = lds_out[(m_*4+1)*256 + lanei*4 + rr] + bff;
                float gg = lds_out[(m_*4+2)*256 + lanei*4 + rr] + bgg;
                float go = lds_out[(m_*4+3)*256 + lanei*4 + rr] + boo;
                float iv = sigm(gi), fv = sigm(gf), gv = tanh_f(gg), ov = sigm(go);
                c = fv*c + iv*gv;
                float h = ov * tanh_f(c);
                f16 hv = (f16)h;
                short hs = __builtin_bit_cast(short, hv);
                __hip_atomic_store((short*)(h1 + (size_t)(s+1)*BH + bg*32768 + jg*512 + tid),
                                   hs, __ATOMIC_RELAXED, __HIP_MEMORY_SCOPE_AGENT);
            }
            __builtin_amdgcn_s_waitcnt(0);   // drain h1 stores
            __syncthreads();
            if (tid == 0) flag_store(flags + bid, (unsigned)(s + 1));
        }
    } else {
        // =================== LAYER 1 ===================
        const int jg1 = bid & 127, j0 = jg1 << 3;
        const int kq = wave >> 1, mh = wave & 1;
        const int kp = (kq & 1) * 512;
        {
            const float* wsrc = (kq < 2) ? wih1 : whh1;
#pragma unroll
            for (int nt = 0; nt < 2; nt++) {
                int ln = (nt << 4) + l15;
                int srcrow = (ln >> 3)*1024 + j0 + (ln & 7);
                const float* rp = wsrc + (size_t)srcrow*1024 + kp + l4*8;
#pragma unroll
                for (int kc = 0; kc < 16; kc++) {
                    float4 a = *(const float4*)(rp + kc*32);
                    float4 b = *(const float4*)(rp + kc*32 + 4);
                    Bf[nt*16 + kc] = cvt8(a, b);
                }
            }
#pragma unroll
            for (int i = 0; i < 32; i++) asm volatile("" : "+v"(Bf[i]));
        }

        const int bm = tid >> 3, u = tid & 7, j = j0 + u;
        const float bi = b1[j], bff = b1[1024+j], bgg = b1[2048+j], boo = b1[3072+j];
        float c = 0.f;
        const int li = ((bm >> 2) & 3) << 4, rr = bm & 3, tI = (bm >> 4) << 1;

        for (int s = 0; s <= T_STEPS; s++) {
            const bool act = (s >= 1);
            if (act) {
#pragma unroll
                for (int i = 0; i < 4; i++) acc[i] = zz;
                if (kq < 2) {
                    // ---- h1 input: gate on all 128 L0 flags ----
                    {
                        const unsigned* p = flags + lane*2;
                        for (;;) {
                            uint2 v = poll2(p);
                            if (__all((v.x >= (unsigned)s) && (v.y >= (unsigned)s))) break;
                            __builtin_amdgcn_s_sleep(2);
                        }
                    }
                    const f16* a0 = h1 + (size_t)s*BH + mh*32768 + (kq*64 + l4)*256 + l15*8;
                    const f16* a1 = a0 + 128;
#pragma unroll
                    for (int kc = 0; kc < 16; kc++) {
                        f16x8 A0 = *(const f16x8*)(a0 + kc*1024);
                        f16x8 A1 = *(const f16x8*)(a1 + kc*1024);
                        acc[0] = __builtin_amdgcn_mfma_f32_16x16x32_f16(A0, Bf[kc],    acc[0], 0,0,0);
                        acc[1] = __builtin_amdgcn_mfma_f32_16x16x32_f16(A0, Bf[16+kc], acc[1], 0,0,0);
                        acc[2] = __builtin_amdgcn_mfma_f32_16x16x32_f16(A1, Bf[kc],    acc[2], 0,0,0);
                        acc[3] = __builtin_amdgcn_mfma_f32_16x16x32_f16(A1, Bf[16+kc], acc[3], 0,0,0);
                    }
                } else if (s == 1) {
                    // h2 init = ones
                    f16x8 A1s;
#pragma unroll
                    for (int e = 0; e < 8; e++) A1s[e] = (f16)1.f;
#pragma unroll
                    for (int kc = 0; kc < 16; kc++) {
                        acc[0] = __builtin_amdgcn_mfma_f32_16x16x32_f16(A1s, Bf[kc],    acc[0], 0,0,0);
                        acc[1] = __builtin_amdgcn_mfma_f32_16x16x32_f16(A1s, Bf[16+kc], acc[1], 0,0,0);
                        acc[2] = __builtin_amdgcn_mfma_f32_16x16x32_f16(A1s, Bf[kc],    acc[2], 0,0,0);
                        acc[3] = __builtin_amdgcn_mfma_f32_16x16x32_f16(A1s, Bf[16+kc], acc[3], 0,0,0);
                    }
                } else {
                    // ---- h2 recurrence: gate on all 128 L1 flags (skip own) ----
                    {
                        const unsigned* p = flags + 128 + lane*2;
                        const bool skip0 = (128 + lane*2     == bid);
                        const bool skip1 = (128 + lane*2 + 1 == bid);
                        for (;;) {
                            uint2 v = poll2(p);
                            if (__all((skip0 || v.x >= (unsigned)s) &&
                                      (skip1 || v.y >= (unsigned)s))) break;
                            __builtin_amdgcn_s_sleep(2);
                        }
                    }
                    const int kq2 = kq - 2;
                    const f16* h2s = h2 + (size_t)((s-1) & 3)*BH;
                    const f16* a0 = h2s + (kq2*64 + l4)*512 + (mh*32 + l15)*8;
                    const f16* a1 = a0 + 128;
#pragma unroll
                    for (int kc = 0; kc < 16; kc++) {
                        f16x8 A0 = ald16(a0 + kc*2048);
                        f16x8 A1 = ald16(a1 + kc*2048);
                        acc[0] = __builtin_amdgcn_mfma_f32_16x16x32_f16(A0, Bf[kc],    acc[0], 0,0,0);
                        acc[1] = __builtin_amdgcn_mfma_f32_16x16x32_f16(A0, Bf[16+kc], acc[1], 0,0,0);
                        acc[2] = __builtin_amdgcn_mfma_f32_16x16x32_f16(A1, Bf[kc],    acc[2], 0,0,0);
                        acc[3] = __builtin_amdgcn_mfma_f32_16x16x32_f16(A1, Bf[16+kc], acc[3], 0,0,0);
                    }
                }
                const int base = kq*2048 + lane*4;
                *(f32x4*)&lds_part[base + ((mh*2+0)*2 + 0)*256] = acc[0];
                *(f32x4*)&lds_part[base + ((mh*2+0)*2 + 1)*256] = acc[1];
                *(f32x4*)&lds_part[base + ((mh*2+1)*2 + 0)*256] = acc[2];
                *(f32x4*)&lds_part[base + ((mh*2+1)*2 + 1)*256] = acc[3];
            }
            __syncthreads();
            if (act) {
                f32x4 sum = *(const f32x4*)&lds_part[tid*4];
                sum += *(const f32x4*)&lds_part[2048 + tid*4];
                sum += *(const f32x4*)&lds_part[4096 + tid*4];
                sum += *(const f32x4*)&lds_part[6144 + tid*4];
                *(f32x4*)&lds_out[tid*4] = sum;
            }
            __syncthreads();
            if (act) {
                float gi = lds_out[(tI+0)*256 + (li +     u)*4 + rr] + bi;
                float gf = lds_out[(tI+0)*256 + (li + 8 + u)*4 + rr] + bff;
                float gg = lds_out[(tI+1)*256 + (li +     u)*4 + rr] + bgg;
                float go = lds_out[(tI+1)*256 + (li + 8 + u)*4 + rr] + boo;
                float iv = sigm(gi), fv = sigm(gf), gv = tanh_f(gg), ov = sigm(go);
                c = fv*c + iv*gv;
                float h = ov * tanh_f(c);
                f16 hv = (f16)h;
                short hs = __builtin_bit_cast(short, hv);
                __hip_atomic_store((short*)(h2 + (size_t)(s & 3)*BH + jg1*512 + tid),
                                   hs, __ATOMIC_RELAXED, __HIP_MEMORY_SCOPE_AGENT);
                out[(size_t)(s-1)*BH + bm*1024 + j] = h;   // pure output: plain store
            }
            __builtin_amdgcn_s_waitcnt(0);   // drain h2 stores before publish
            __syncthreads();
            if (tid == 0) flag_store(flags + bid, (unsigned)(s + 1));
        }
    }
}

extern "C" void kernel_launch(void* const* d_in, const int* in_sizes, int n_in,
                              void* d_out, int out_size, void* d_ws, size_t ws_size,
                              hipStream_t stream) {
    const float* x    = (const float*)d_in[0];
    const float* wih0 = (const float*)d_in[1];
    const float* whh0 = (const float*)d_in[2];
    const float* b0   = (const float*)d_in[3];
    const float* wih1 = (const float*)d_in[4];
    const float* whh1 = (const float*)d_in[5];
    const float* b1   = (const float*)d_in[6];
    float* out = (float*)d_out;

    char* ws = (char*)d_ws;
    unsigned* flags = (unsigned*)(ws + OFF_FLAG);
    f16* h2         = (f16*)(ws + OFF_H2);
    f16* h1         = (f16*)(ws + OFF_H1);

    prep_kernel<<<256, 256, 0, stream>>>(h1, flags);
    lstm_kernel<<<NBLK, 512, 0, stream>>>(x, wih0, whh0, b0, wih1, whh1, b1,
                                          h1, h2, out, flags);
}

// Round 2
// 4889.280 us; speedup vs baseline: 1.4368x; 1.0665x over previous
//
#include <hip/hip_runtime.h>
#include <cstdint>
#include <cstddef>

// ---------------------------------------------------------------------------
// 2-layer LSTM, T=512, B=64, IN=H=1024. Persistent kernel, 192 blocks x 512
// threads, layers pipelined at lag 1.
// R6 changes (theory: remaining step time is the zero-reuse L3 read paths —
// L1's full-token h1 (16 MB/step) and h2 agent-atomic ring (16 MB/step) —
// plus global-barrier straggler coupling):
//  - L1 repartitioned 64 blocks x 16 units x 64 batches (weight-VGPR cap,
//    same scheme as L0). L1 h1 fan-out 16->8 MB/step, h2 8 MB/step, flag
//    fan-in halves, 64 fewer blocks in the straggler pool.
//  - Per-slice flag gating: each consumer wave polls ONLY its K-slice's
//    producers (16-32 flags), not the full peer set. Block-level union over
//    waves still equals the full set, so the h2 ring-4 WAR invariant holds
//    (a block's step-s write still implies all peers >= s).
//  - LDS 144 KB/block (8 wave-regions x 16 KB partials + 16 KB out).
// ---------------------------------------------------------------------------

typedef _Float16 f16;
typedef _Float16 f16x8 __attribute__((ext_vector_type(8)));
typedef _Float16 f16x4 __attribute__((ext_vector_type(4)));
typedef float    f32x4 __attribute__((ext_vector_type(4)));
typedef unsigned long long u64;

#define T_STEPS 512
#define BH      65536                 /* 64 batch x 1024 hidden */
#define NBLK    192

// workspace layout (bytes)
static const size_t OFF_FLAG = 0;            // 256 x 4 B flags (192 used)
static const size_t OFF_H2   = 0x1000;       // h2 ring: 4 slabs * BH * 2B = 512 KB
static const size_t OFF_H1   = 0x90000;      // h1 history: 513 slabs * BH * 2B = 64.1 MB
// h1 slab layout: slab*65536 + (b>>5)*32768 + (k>>3)*256 + (b&31)*8 + (k&7)  (f16)
// h2 slab layout: slab*65536 + (k>>3)*512  + b*8 + (k&7)                     (f16)

// ---------------------------------------------------------------------------
__global__ void prep_kernel(f16* __restrict__ h1, unsigned* __restrict__ flags)
{
    const int NONES = BH / 4;                 // slab 0 = ones (h init)
    const int NZ    = 256 / 4;
    int tid    = blockIdx.x * blockDim.x + threadIdx.x;
    int stride = gridDim.x * blockDim.x;
    f16x4 one = { (f16)1.f, (f16)1.f, (f16)1.f, (f16)1.f };
    uint4 z = { 0u, 0u, 0u, 0u };
    for (int i = tid; i < NONES + NZ; i += stride) {
        if (i < NONES) ((f16x4*)h1)[i] = one;
        else           ((uint4*)flags)[i - NONES] = z;
    }
}

__device__ __forceinline__ float sigm(float x) { return 1.f/(1.f + __expf(-x)); }
__device__ __forceinline__ float tanh_f(float x) {
    float e = __expf(-2.f*fabsf(x));
    float r = (1.f - e)/(1.f + e);
    return x >= 0.f ? r : -r;
}
__device__ __forceinline__ f16x8 cvt8(float4 a, float4 b) {
    f16x8 r;
    r[0]=(f16)a.x; r[1]=(f16)a.y; r[2]=(f16)a.z; r[3]=(f16)a.w;
    r[4]=(f16)b.x; r[5]=(f16)b.y; r[6]=(f16)b.z; r[7]=(f16)b.w;
    return r;
}

// L2-bypass (device-scope) poll load.
__device__ __forceinline__ unsigned poll1(const unsigned* p) {
    unsigned r;
    asm volatile("global_load_dword %0, %1, off sc1\n\ts_waitcnt vmcnt(0)"
                 : "=v"(r) : "v"(p) : "memory");
    return r;
}
// L2-bypass (device-scope) flag publish.
__device__ __forceinline__ void flag_store(unsigned* p, unsigned v) {
    asm volatile("global_store_dword %0, %1, off sc1" :: "v"(p), "v"(v) : "memory");
}
// Coherent 16-B load as 2x agent-scope u64 (h2 ring reuses addresses; the
// consumer's per-XCD L2 could hold stale lines, so bypass it).
__device__ __forceinline__ f16x8 ald16(const f16* p) {
    union { u64 q[2]; f16x8 v; } u;
    u.q[0] = __hip_atomic_load((const u64*)p,       __ATOMIC_RELAXED, __HIP_MEMORY_SCOPE_AGENT);
    u.q[1] = __hip_atomic_load((const u64*)(p + 4), __ATOMIC_RELAXED, __HIP_MEMORY_SCOPE_AGENT);
    return u.v;
}

// ---------------------------------------------------------------------------
// Partition:
//  Layer 0 (bid 0..127): bg = bid>>6 (batch group of 32), jg = bid&63
//    (16 units, j0=jg*16). 8 waves = 8 K-slices of 256 over K=2048 [x | h1];
//    waves 0-3 = x (ungated), waves 4-7 = h1, each gated on the 16 producers
//    of its K-slice. 4 n-tiles/wave = gates i,f,g,o x 16 units; 2 m-tiles.
//  Layer 1 (bid 128..191): jg1 = bid-128 (16 units, j0=jg1*16), all 64
//    batches. 8 waves = 8 K-slices of 256 over K=2048 [h1 | h2]; waves 0-3 =
//    h1 (gated on the 32 L0 producers of the slice), waves 4-7 = h2 ring
//    (gated on the 16 L1 producers; ones at s==1). 4 n-tiles x 4 m-tiles.
// Step s: L0 computes h1 token s -> slab s+1; L1 computes out token s-1
//    (h1 slab s + h2 ring slab (s-1)&3), writes out + h2 slab s&3.
// ---------------------------------------------------------------------------
__global__ __launch_bounds__(512, 2)
void lstm_kernel(const float* __restrict__ x,
                 const float* __restrict__ wih0, const float* __restrict__ whh0,
                 const float* __restrict__ b0,
                 const float* __restrict__ wih1, const float* __restrict__ whh1,
                 const float* __restrict__ b1,
                 f16* __restrict__ h1, f16* __restrict__ h2,
                 float* __restrict__ out, unsigned* __restrict__ flags)
{
    __shared__ float lds_part[32768];   // 8 wave-regions x 4096 floats
    __shared__ float lds_out[4096];

    const int tid   = threadIdx.x;
    const int bid   = blockIdx.x;
    const int wave  = tid >> 6, lane = tid & 63;
    const int l15   = lane & 15, l4 = lane >> 4;
    const f32x4 zz = { 0.f, 0.f, 0.f, 0.f };

    if (bid < 128) {
        // =================== LAYER 0 ===================
        const int bg = bid >> 6, jg = bid & 63, j0 = jg << 4;
        const int kq = wave;                    // 0..3: x-slice, 4..7: h-slice

        f16x8 Bf[32];
        f32x4 acc[8];
        {
            const float* wsrc = (kq < 4) ? wih0 : whh0;
            const int kp = (kq & 3) * 256;
#pragma unroll
            for (int nt = 0; nt < 4; nt++) {
                const float* rp = wsrc + (size_t)(nt*1024 + j0 + l15)*1024 + kp + l4*8;
#pragma unroll
                for (int kc = 0; kc < 8; kc++) {
                    float4 a = *(const float4*)(rp + kc*32);
                    float4 b = *(const float4*)(rp + kc*32 + 4);
                    Bf[nt*8 + kc] = cvt8(a, b);
                }
            }
#pragma unroll
            for (int i = 0; i < 32; i++) asm volatile("" : "+v"(Bf[i]));
        }

        const int u  = ((tid >> 8) << 3) | (tid & 7);   // unit 0..15
        const int bm = (tid >> 3) & 31;                 // batch-in-group 0..31
        const float bi  = b0[j0+u],      bff = b0[1024+j0+u];
        const float bgg = b0[2048+j0+u], boo = b0[3072+j0+u];
        float c = 0.f;
        const int m_ = bm >> 4, r_ = bm & 15;
        const int lanei = ((r_ >> 2) << 4) | u, rr = r_ & 3;

        for (int s = 0; s <= T_STEPS; s++) {
            const bool act = (s < T_STEPS);
            if (act) {
#pragma unroll
                for (int i = 0; i < 8; i++) acc[i] = zz;
                if (kq < 4) {
                    // ---- x-part: ungated, overlaps peers' straggle ----
                    const float* a0 = x + (size_t)s*BH + (size_t)(bg*32 + l15)*1024 + kq*256 + l4*8;
                    const float* a1 = a0 + 16*1024;
#pragma unroll
                    for (int kc = 0; kc < 8; kc++) {
                        f16x8 A0 = cvt8(*(const float4*)(a0 + kc*32), *(const float4*)(a0 + kc*32 + 4));
                        f16x8 A1 = cvt8(*(const float4*)(a1 + kc*32), *(const float4*)(a1 + kc*32 + 4));
#pragma unroll
                        for (int nt = 0; nt < 4; nt++) {
                            acc[nt]   = __builtin_amdgcn_mfma_f32_16x16x32_f16(A0, Bf[nt*8+kc], acc[nt],   0,0,0);
                            acc[4+nt] = __builtin_amdgcn_mfma_f32_16x16x32_f16(A1, Bf[nt*8+kc], acc[4+nt], 0,0,0);
                        }
                    }
                } else {
                    // ---- h-part: gate on the 16 producers of this K-slice ----
                    if (s > 0) {
                        const bool mine = (lane < 16);
                        const int  pj   = ((kq - 4) << 4) + l15;     // producer jg
                        const bool skip = (!mine) || (pj == jg);
                        const unsigned* p = flags + bg*64 + (mine ? pj : 0);
                        for (;;) {
                            unsigned v = poll1(p);
                            if (__all(skip || (v >= (unsigned)s))) break;
                            __builtin_amdgcn_s_sleep(2);
                        }
                    }
                    const f16* a0 = h1 + (size_t)s*BH + bg*32768 + ((kq-4)*32 + l4)*256 + l15*8;
                    const f16* a1 = a0 + 128;
#pragma unroll
                    for (int kc = 0; kc < 8; kc++) {
                        f16x8 A0 = *(const f16x8*)(a0 + kc*1024);
                        f16x8 A1 = *(const f16x8*)(a1 + kc*1024);
#pragma unroll
                        for (int nt = 0; nt < 4; nt++) {
                            acc[nt]   = __builtin_amdgcn_mfma_f32_16x16x32_f16(A0, Bf[nt*8+kc], acc[nt],   0,0,0);
                            acc[4+nt] = __builtin_amdgcn_mfma_f32_16x16x32_f16(A1, Bf[nt*8+kc], acc[4+nt], 0,0,0);
                        }
                    }
                }
                const int pb = wave*2048 + lane*4;
#pragma unroll
                for (int i = 0; i < 8; i++)
                    *(f32x4*)&lds_part[pb + i*256] = acc[i];
            }
            __syncthreads();
            if (act) {
                f32x4 sum = *(const f32x4*)&lds_part[tid*4];
#pragma unroll
                for (int q = 1; q < 8; q++)
                    sum += *(const f32x4*)&lds_part[q*2048 + tid*4];
                *(f32x4*)&lds_out[tid*4] = sum;
            }
            __syncthreads();
            if (act) {
                float gi = lds_out[(m_*4+0)*256 + lanei*4 + rr] + bi;
                float gf = lds_out[(m_*4+1)*256 + lanei*4 + rr] + bff;
                float gg = lds_out[(m_*4+2)*256 + lanei*4 + rr] + bgg;
                float go = lds_out[(m_*4+3)*256 + lanei*4 + rr] + boo;
                float iv = sigm(gi), fv = sigm(gf), gv = tanh_f(gg), ov = sigm(go);
                c = fv*c + iv*gv;
                float h = ov * tanh_f(c);
                f16 hv = (f16)h;
                short hs = __builtin_bit_cast(short, hv);
                __hip_atomic_store((short*)(h1 + (size_t)(s+1)*BH + bg*32768 + jg*512 + tid),
                                   hs, __ATOMIC_RELAXED, __HIP_MEMORY_SCOPE_AGENT);
            }
            __builtin_amdgcn_s_waitcnt(0);   // drain h1 stores
            __syncthreads();
            if (tid == 0) flag_store(flags + bid, (unsigned)(s + 1));
        }
    } else {
        // =================== LAYER 1 ===================
        const int jg1 = bid - 128, j0 = jg1 << 4;
        const int ks = wave;                    // 0..3: h1-slice, 4..7: h2-slice

        f16x8 Bf[32];
        f32x4 acc[16];
        {
            const float* wsrc = (ks < 4) ? wih1 : whh1;
            const int kp = (ks & 3) * 256;
#pragma unroll
            for (int nt = 0; nt < 4; nt++) {
                const float* rp = wsrc + (size_t)(nt*1024 + j0 + l15)*1024 + kp + l4*8;
#pragma unroll
                for (int kc = 0; kc < 8; kc++) {
                    float4 a = *(const float4*)(rp + kc*32);
                    float4 b = *(const float4*)(rp + kc*32 + 4);
                    Bf[nt*8 + kc] = cvt8(a, b);
                }
            }
#pragma unroll
            for (int i = 0; i < 32; i++) asm volatile("" : "+v"(Bf[i]));
        }

        // two cells per thread: (bb, u0) and (bb, u1)
        const int bb = tid >> 3, u0 = tid & 7, u1 = 8 + u0;
        const float bi0 = b1[j0+u0], bf0 = b1[1024+j0+u0], bg0v = b1[2048+j0+u0], bo0 = b1[3072+j0+u0];
        const float bi1 = b1[j0+u1], bf1 = b1[1024+j0+u1], bg1v = b1[2048+j0+u1], bo1 = b1[3072+j0+u1];
        float c0 = 0.f, c1 = 0.f;
        const int mt_ = bb >> 4, r_ = bb & 15, rr = r_ & 3, lb = (r_ >> 2) << 4;

        for (int s = 0; s <= T_STEPS; s++) {
            const bool act = (s >= 1);
            if (act) {
#pragma unroll
                for (int i = 0; i < 16; i++) acc[i] = zz;
                if (ks < 4) {
                    // ---- h1 input: gate on the 32 L0 producers of this slice ----
                    {
                        const bool mine = (lane < 32);
                        const int  pidx = ((lane >> 4) * 64) + (ks << 4) + l15;
                        const unsigned* p = flags + (mine ? pidx : 0);
                        for (;;) {
                            unsigned v = poll1(p);
                            if (__all(!mine || (v >= (unsigned)s))) break;
                            __builtin_amdgcn_s_sleep(2);
                        }
                    }
                    const f16* a0 = h1 + (size_t)s*BH + (ks*32 + l4)*256 + l15*8;
#pragma unroll
                    for (int kc = 0; kc < 8; kc++) {
                        f16x8 A0 = *(const f16x8*)(a0 + kc*1024);
                        f16x8 A1 = *(const f16x8*)(a0 + kc*1024 + 128);
                        f16x8 A2 = *(const f16x8*)(a0 + kc*1024 + 32768);
                        f16x8 A3 = *(const f16x8*)(a0 + kc*1024 + 32768 + 128);
#pragma unroll
                        for (int nt = 0; nt < 4; nt++) {
                            acc[nt]    = __builtin_amdgcn_mfma_f32_16x16x32_f16(A0, Bf[nt*8+kc], acc[nt],    0,0,0);
                            acc[4+nt]  = __builtin_amdgcn_mfma_f32_16x16x32_f16(A1, Bf[nt*8+kc], acc[4+nt],  0,0,0);
                            acc[8+nt]  = __builtin_amdgcn_mfma_f32_16x16x32_f16(A2, Bf[nt*8+kc], acc[8+nt],  0,0,0);
                            acc[12+nt] = __builtin_amdgcn_mfma_f32_16x16x32_f16(A3, Bf[nt*8+kc], acc[12+nt], 0,0,0);
                        }
                    }
                } else if (s == 1) {
                    // h2 init = ones
                    f16x8 A1s;
#pragma unroll
                    for (int e = 0; e < 8; e++) A1s[e] = (f16)1.f;
#pragma unroll
                    for (int kc = 0; kc < 8; kc++) {
#pragma unroll
                        for (int nt = 0; nt < 4; nt++) {
                            acc[nt]    = __builtin_amdgcn_mfma_f32_16x16x32_f16(A1s, Bf[nt*8+kc], acc[nt],    0,0,0);
                            acc[4+nt]  = __builtin_amdgcn_mfma_f32_16x16x32_f16(A1s, Bf[nt*8+kc], acc[4+nt],  0,0,0);
                            acc[8+nt]  = __builtin_amdgcn_mfma_f32_16x16x32_f16(A1s, Bf[nt*8+kc], acc[8+nt],  0,0,0);
                            acc[12+nt] = __builtin_amdgcn_mfma_f32_16x16x32_f16(A1s, Bf[nt*8+kc], acc[12+nt], 0,0,0);
                        }
                    }
                } else {
                    // ---- h2 recurrence: gate on the 16 L1 producers (skip own) ----
                    {
                        const bool mine = (lane < 16);
                        const int  pj   = ((ks - 4) << 4) + l15;     // producer jg1
                        const bool skip = (!mine) || (pj == jg1);
                        const unsigned* p = flags + 128 + (mine ? pj : 0);
                        for (;;) {
                            unsigned v = poll1(p);
                            if (__all(skip || (v >= (unsigned)s))) break;
                            __builtin_amdgcn_s_sleep(2);
                        }
                    }
                    const f16* a0 = h2 + (size_t)((s-1) & 3)*BH + ((ks-4)*32 + l4)*512 + l15*8;
#pragma unroll
                    for (int kc = 0; kc < 8; kc++) {
                        f16x8 A0 = ald16(a0 + kc*2048);
                        f16x8 A1 = ald16(a0 + kc*2048 + 128);
                        f16x8 A2 = ald16(a0 + kc*2048 + 256);
                        f16x8 A3 = ald16(a0 + kc*2048 + 384);
#pragma unroll
                        for (int nt = 0; nt < 4; nt++) {
                            acc[nt]    = __builtin_amdgcn_mfma_f32_16x16x32_f16(A0, Bf[nt*8+kc], acc[nt],    0,0,0);
                            acc[4+nt]  = __builtin_amdgcn_mfma_f32_16x16x32_f16(A1, Bf[nt*8+kc], acc[4+nt],  0,0,0);
                            acc[8+nt]  = __builtin_amdgcn_mfma_f32_16x16x32_f16(A2, Bf[nt*8+kc], acc[8+nt],  0,0,0);
                            acc[12+nt] = __builtin_amdgcn_mfma_f32_16x16x32_f16(A3, Bf[nt*8+kc], acc[12+nt], 0,0,0);
                        }
                    }
                }
                const int pb = ks*4096 + lane*4;
#pragma unroll
                for (int i = 0; i < 16; i++)
                    *(f32x4*)&lds_part[pb + i*256] = acc[i];
            }
            __syncthreads();
            if (act) {
#pragma unroll
                for (int g = 0; g < 2; g++) {
                    const int gi_ = tid + g*512;
                    f32x4 sum = *(const f32x4*)&lds_part[gi_*4];
#pragma unroll
                    for (int q = 1; q < 8; q++)
                        sum += *(const f32x4*)&lds_part[q*4096 + gi_*4];
                    *(f32x4*)&lds_out[gi_*4] = sum;
                }
            }
            __syncthreads();
            if (act) {
                float gi0 = lds_out[(mt_*4+0)*256 + (lb+u0)*4 + rr] + bi0;
                float gf0 = lds_out[(mt_*4+1)*256 + (lb+u0)*4 + rr] + bf0;
                float gg0 = lds_out[(mt_*4+2)*256 + (lb+u0)*4 + rr] + bg0v;
                float go0 = lds_out[(mt_*4+3)*256 + (lb+u0)*4 + rr] + bo0;
                float gi1 = lds_out[(mt_*4+0)*256 + (lb+u1)*4 + rr] + bi1;
                float gf1 = lds_out[(mt_*4+1)*256 + (lb+u1)*4 + rr] + bf1;
                float gg1 = lds_out[(mt_*4+2)*256 + (lb+u1)*4 + rr] + bg1v;
                float go1 = lds_out[(mt_*4+3)*256 + (lb+u1)*4 + rr] + bo1;
                float iv0 = sigm(gi0), fv0 = sigm(gf0), gv0 = tanh_f(gg0), ov0 = sigm(go0);
                float iv1 = sigm(gi1), fv1 = sigm(gf1), gv1 = tanh_f(gg1), ov1 = sigm(go1);
                c0 = fv0*c0 + iv0*gv0;
                c1 = fv1*c1 + iv1*gv1;
                float hv0 = ov0 * tanh_f(c0);
                float hv1 = ov1 * tanh_f(c1);
                f16* h2w = h2 + (size_t)(s & 3)*BH;
                short hs0 = __builtin_bit_cast(short, (f16)hv0);
                short hs1 = __builtin_bit_cast(short, (f16)hv1);
                __hip_atomic_store((short*)(h2w + jg1*1024 + tid),       hs0,
                                   __ATOMIC_RELAXED, __HIP_MEMORY_SCOPE_AGENT);
                __hip_atomic_store((short*)(h2w + jg1*1024 + 512 + tid), hs1,
                                   __ATOMIC_RELAXED, __HIP_MEMORY_SCOPE_AGENT);
                out[(size_t)(s-1)*BH + bb*1024 + j0 + u0] = hv0;   // pure output
                out[(size_t)(s-1)*BH + bb*1024 + j0 + u1] = hv1;
            }
            __builtin_amdgcn_s_waitcnt(0);   // drain h2 stores before publish
            __syncthreads();
            if (tid == 0) flag_store(flags + bid, (unsigned)(s + 1));
        }
    }
}

extern "C" void kernel_launch(void* const* d_in, const int* in_sizes, int n_in,
                              void* d_out, int out_size, void* d_ws, size_t ws_size,
                              hipStream_t stream) {
    const float* x    = (const float*)d_in[0];
    const float* wih0 = (const float*)d_in[1];
    const float* whh0 = (const float*)d_in[2];
    const float* b0   = (const float*)d_in[3];
    const float* wih1 = (const float*)d_in[4];
    const float* whh1 = (const float*)d_in[5];
    const float* b1   = (const float*)d_in[6];
    float* out = (float*)d_out;

    char* ws = (char*)d_ws;
    unsigned* flags = (unsigned*)(ws + OFF_FLAG);
    f16* h2         = (f16*)(ws + OFF_H2);
    f16* h1         = (f16*)(ws + OFF_H1);

    prep_kernel<<<256, 256, 0, stream>>>(h1, flags);
    lstm_kernel<<<NBLK, 512, 0, stream>>>(x, wih0, whh0, b0, wih1, whh1, b1,
                                          h1, h2, out, flags);
}